// Round 4
// baseline (165.187 us; speedup 1.0000x reference)
//
#include <hip/hip_runtime.h>

#define DSZ 96
#define CIN 16
#define NF  16

typedef __attribute__((ext_vector_type(8))) short short8;   // 8 bf16
typedef __attribute__((ext_vector_type(4))) float f32x4;    // MFMA C/D

union I4S8 { int4 i; short8 s; };

// ---------------- prepass: pack w into B-fragment layout (validated R2/R3) --
// k = ((lane>>4)&1)*8 + j ; tap = 2t + (lane>>5) ; tap 27 -> zeros.
__global__ void pack_w(const float* __restrict__ w, short* __restrict__ wpack) {
  const int t = threadIdx.x >> 6;   // 0..13
  const int l = threadIdx.x & 63;
  const int tap = 2 * t + (l >> 5);
  const int cib = ((l >> 4) & 1) * 8;
  const int f = l & 15;
  short v[8];
#pragma unroll
  for (int j = 0; j < 8; ++j) {
    float x = (tap <= 26) ? w[(tap * 16 + cib + j) * 16 + f] : 0.0f;
    unsigned u = __float_as_uint(x);
    u = (u + 0x7FFFu + ((u >> 16) & 1u)) >> 16;  // RNE to bf16
    v[j] = (short)u;
  }
  short8 s;
#pragma unroll
  for (int j = 0; j < 8; ++j) s[j] = v[j];
  reinterpret_cast<short8*>(wpack)[t * 64 + l] = s;
}

// ---------------- main: slab-pipelined LDS MFMA conv ----------------
// Block = 1024 threads (16 waves) = 8x8 xy tile x 48 z (3 slabs of 16).
// Wave w: cx = w&7, cy in [ (w>>3)*4, +4 ).  Per slab: stage 10x10x18 bf16
// halo; fragments read via per-lane constant address + offset-immediate.
__global__ __launch_bounds__(1024, 4) void conv_mfma_pipe(
    const float* __restrict__ feat, const int* __restrict__ index,
    const float* __restrict__ bias, const short8* __restrict__ wpack,
    float* __restrict__ out) {
  __shared__ short smem[100 * 18 * 16];   // 57600 B

  const int tid  = threadIdx.x;
  const int lane = tid & 63;
  const int wid  = tid >> 6;

  // XCD-aware bijective swizzle (1152 % 8 == 0, chunk = 144); yt fastest so
  // consecutive logical blocks on one XCD share x-halo columns in L2.
  const int d = blockIdx.x;
  int L = (d & 7) * 144 + (d >> 3);
  const int yt = L % 12;  L /= 12;
  const int xt = L % 12;  L /= 12;
  const int zb = L & 1;
  const int b  = L >> 1;
  const int x0 = xt * 8, y0 = yt * 8, zbase = zb * 48;

  // B fragments resident (56 VGPRs)
  short8 bw[14];
#pragma unroll
  for (int t = 0; t < 14; ++t) bw[t] = wpack[t * 64 + lane];

  // ---- per-lane fragment read addresses (swizzle folded: col bases are
  // multiples of 32, XOR touches only bit 4 of the zp*32+h16 part) ----
  const int cx = wid & 7, cyh = wid >> 3;
  const int wbase = (cx * 10 + cyh * 4) * 576;
  int pre[3];
#pragma unroll
  for (int dz = 0; dz < 3; ++dz) {
    const int zp = (lane & 15) + dz;
    pre[dz] = (zp * 32 + (lane & 16)) ^ ((zp & 4) << 2);
  }
  int laddr[14];
#pragma unroll
  for (int t = 0; t < 14; ++t) {
    const int tapA = 2 * t;
    const int tapB = (2 * t + 1 <= 26) ? (2 * t + 1) : 26;  // t13: B==0
    const int cA = ((tapA / 9) * 10 + (tapA / 3) % 3) * 576;
    const int cB = ((tapB / 9) * 10 + (tapB / 3) % 3) * 576;
    const int aA = cA + pre[tapA % 3];
    const int aB = cB + pre[tapB % 3];
    laddr[t] = ((lane >> 5) ? aB : aA) + wbase;
  }

  const int fq = lane & 15, hq = lane >> 4;
  const float bf = bias[fq];
  const char* smb = (const char*)smem;

  // ---- staging state: up to 4 granules/thread (8 ci each), f32 held ----
  float4 sf[4][2];
  int    sok[4];

  auto stage_issue = [&](int z0) {
#pragma unroll
    for (int k = 0; k < 4; ++k) {
      const int i = tid + k * 1024;
      const int col = i / 36;
      const int r = i - col * 36;
      const int zp = r >> 1, g = r & 1;
      const int colx = col / 10, coly = col - colx * 10;
      const int gx = x0 + colx - 1, gy = y0 + coly - 1, gz = z0 - 1 + zp;
      const bool ok = (i < 3600) & ((unsigned)gx < (unsigned)DSZ) &
                      ((unsigned)gy < (unsigned)DSZ) &
                      ((unsigned)gz < (unsigned)DSZ);
      const long off =
          ok ? ((long)(((b * DSZ + gx) * DSZ + gy) * DSZ + gz) * CIN + g * 8) : 0;
      const float4* p = reinterpret_cast<const float4*>(feat + off);
      sf[k][0] = p[0];
      sf[k][1] = p[1];
      sok[k] = ok;
    }
  };

  auto stage_write = [&]() {
#pragma unroll
    for (int k = 0; k < 4; ++k) {
      const int i = tid + k * 1024;
      if (i < 3600) {
        const int col = i / 36;
        const int r = i - col * 36;
        const int zp = r >> 1, g = r & 1;
        unsigned m0 = __builtin_amdgcn_perm(__float_as_uint(sf[k][0].y),
                                            __float_as_uint(sf[k][0].x), 0x07060302u);
        unsigned m1 = __builtin_amdgcn_perm(__float_as_uint(sf[k][0].w),
                                            __float_as_uint(sf[k][0].z), 0x07060302u);
        unsigned m2 = __builtin_amdgcn_perm(__float_as_uint(sf[k][1].y),
                                            __float_as_uint(sf[k][1].x), 0x07060302u);
        unsigned m3 = __builtin_amdgcn_perm(__float_as_uint(sf[k][1].w),
                                            __float_as_uint(sf[k][1].z), 0x07060302u);
        if (!sok[k]) { m0 = 0u; m1 = 0u; m2 = 0u; m3 = 0u; }
        const int byte = (col * 576 + zp * 32 + g * 16) ^ ((zp & 4) << 2);
        *reinterpret_cast<int4*>((char*)smem + byte) = make_int4(m0, m1, m2, m3);
      }
    }
  };

  auto compute = [&](int z0) {
#pragma unroll
    for (int j = 0; j < 4; ++j) {
      f32x4 acc0 = {0.f, 0.f, 0.f, 0.f};
      f32x4 acc1 = {0.f, 0.f, 0.f, 0.f};
#pragma unroll
      for (int t = 0; t < 14; ++t) {
        I4S8 u;
        u.i = *reinterpret_cast<const int4*>(smb + laddr[t] + j * 576);
        if (t & 1)
          acc1 = __builtin_amdgcn_mfma_f32_16x16x32_bf16(u.s, bw[t], acc1, 0, 0, 0);
        else
          acc0 = __builtin_amdgcn_mfma_f32_16x16x32_bf16(u.s, bw[t], acc0, 0, 0, 0);
      }
      const int gy = y0 + cyh * 4 + j;
      const int vbase = ((b * DSZ + (x0 + cx)) * DSZ + gy) * DSZ + z0;
      const int4 iv = *reinterpret_cast<const int4*>(index + vbase + hq * 4);
      float* op = out + (long)(vbase + hq * 4) * NF + fq;
      op[0 * NF] = iv.x ? (acc0[0] + acc1[0] + bf) : 0.0f;
      op[1 * NF] = iv.y ? (acc0[1] + acc1[1] + bf) : 0.0f;
      op[2 * NF] = iv.z ? (acc0[2] + acc1[2] + bf) : 0.0f;
      op[3 * NF] = iv.w ? (acc0[3] + acc1[3] + bf) : 0.0f;
    }
  };

  // ---- slab pipeline: loads for s+1 in flight during compute of s ----
  stage_issue(zbase);
  stage_write();
  __syncthreads();

  stage_issue(zbase + 16);
  compute(zbase);
  __syncthreads();
  stage_write();
  __syncthreads();

  stage_issue(zbase + 32);
  compute(zbase + 16);
  __syncthreads();
  stage_write();
  __syncthreads();

  compute(zbase + 32);
}

// ---------------- fallback (tiny ws): round-1 f32 kernel ----------------
__global__ __launch_bounds__(256) void sparse_conv_f32(
    const float* __restrict__ feat, const int* __restrict__ index,
    const float* __restrict__ w, const float* __restrict__ bias,
    float* __restrict__ out) {
  const int v = blockIdx.x * 256 + threadIdx.x;
  const int z = v % DSZ;
  int t = v / DSZ;
  const int y = t % DSZ; t /= DSZ;
  const int x = t % DSZ;
  const int bb = t / DSZ;
  float acc[NF];
#pragma unroll
  for (int f = 0; f < NF; ++f) acc[f] = bias[f];
  const bool active = (index[v] != 0);
#pragma unroll 1
  for (int kx = -1; kx <= 1; ++kx) {
    const int xx = x + kx;
    const bool okx = ((unsigned)xx < (unsigned)DSZ);
#pragma unroll 1
    for (int ky = -1; ky <= 1; ++ky) {
      const int yy = y + ky;
      const bool oky = okx && ((unsigned)yy < (unsigned)DSZ);
#pragma unroll 1
      for (int kz = -1; kz <= 1; ++kz) {
        const int zz = z + kz;
        const bool ok = oky && ((unsigned)zz < (unsigned)DSZ);
        const long long off = ((((long long)bb * DSZ + xx) * DSZ + yy) * DSZ + zz) * CIN;
        float4 q0, q1, q2, q3;
        if (ok) {
          const float4* fp = reinterpret_cast<const float4*>(feat + off);
          q0 = fp[0]; q1 = fp[1]; q2 = fp[2]; q3 = fp[3];
        } else {
          q0 = q1 = q2 = q3 = make_float4(0.f, 0.f, 0.f, 0.f);
        }
        const float fv[CIN] = {q0.x, q0.y, q0.z, q0.w, q1.x, q1.y, q1.z, q1.w,
                               q2.x, q2.y, q2.z, q2.w, q3.x, q3.y, q3.z, q3.w};
        const float* wr = w + ((((kx + 1) * 3 + (ky + 1)) * 3 + (kz + 1)) * CIN) * NF;
#pragma unroll
        for (int ci = 0; ci < CIN; ++ci) {
          const float fvv = fv[ci];
#pragma unroll
          for (int f = 0; f < NF; ++f) acc[f] = fmaf(fvv, wr[ci * NF + f], acc[f]);
        }
      }
    }
  }
  float4* op = reinterpret_cast<float4*>(out + (long long)v * NF);
  if (active) {
    op[0] = make_float4(acc[0], acc[1], acc[2], acc[3]);
    op[1] = make_float4(acc[4], acc[5], acc[6], acc[7]);
    op[2] = make_float4(acc[8], acc[9], acc[10], acc[11]);
    op[3] = make_float4(acc[12], acc[13], acc[14], acc[15]);
  } else {
    const float4 z4 = make_float4(0.f, 0.f, 0.f, 0.f);
    op[0] = z4; op[1] = z4; op[2] = z4; op[3] = z4;
  }
}

extern "C" void kernel_launch(void* const* d_in, const int* in_sizes, int n_in,
                              void* d_out, int out_size, void* d_ws, size_t ws_size,
                              hipStream_t stream) {
  const float* feat  = (const float*)d_in[0];
  const int*   index = (const int*)d_in[1];
  const float* w     = (const float*)d_in[2];
  const float* bias  = (const float*)d_in[3];
  float*       out   = (float*)d_out;

  const int nvox = in_sizes[1];  // 4*96*96*96

  if (ws_size < 14 * 64 * 8 * sizeof(short)) {
    sparse_conv_f32<<<nvox / 256, 256, 0, stream>>>(feat, index, w, bias, out);
    return;
  }

  short* wpack = (short*)d_ws;
  pack_w<<<1, 14 * 64, 0, stream>>>(w, wpack);

  const int blocks = 4 * 2 * 12 * 12;  // 1152
  conv_mfma_pipe<<<blocks, 1024, 0, stream>>>(feat, index, bias,
                                              (const short8*)wpack, out);
}

// Round 6
// 131.432 us; speedup vs baseline: 1.2568x; 1.2568x over previous
//
#include <hip/hip_runtime.h>

#define DSZ 96
#define CIN 16
#define NF  16
#define NXT (DSZ / 8)    // 12
#define NYT (DSZ / 8)    // 12
#define NZT (DSZ / 16)   // 6

typedef __attribute__((ext_vector_type(8))) short short8;   // 8 bf16
typedef __attribute__((ext_vector_type(4))) float f32x4;    // MFMA C/D

union I4S8 { int4 i; short8 s; };

// ---------------- prepass: pack w into B-fragment layout (validated) -------
// k = ((lane>>4)&1)*8 + j ; tap = 2t + (lane>>5) ; tap 27 -> zeros.
__global__ void pack_w(const float* __restrict__ w, short* __restrict__ wpack) {
  const int t = threadIdx.x >> 6;   // 0..13
  const int l = threadIdx.x & 63;
  const int tap = 2 * t + (l >> 5);
  const int cib = ((l >> 4) & 1) * 8;
  const int f = l & 15;
  short v[8];
#pragma unroll
  for (int j = 0; j < 8; ++j) {
    float x = (tap <= 26) ? w[(tap * 16 + cib + j) * 16 + f] : 0.0f;
    unsigned u = __float_as_uint(x);
    u = (u + 0x7FFFu + ((u >> 16) & 1u)) >> 16;  // RNE to bf16
    v[j] = (short)u;
  }
  short8 s;
#pragma unroll
  for (int j = 0; j < 8; ++j) s[j] = v[j];
  reinterpret_cast<short8*>(wpack)[t * 64 + l] = s;
}

// ---------------- main: LDS-staged MFMA conv (R3 + zero-VALU addressing) ---
// Block = 512 threads (8 waves) = 8x8 xy columns x 16 z outputs.
// Fragment addresses precomputed per lane; cy advances via offset immediate
// (576 = 9*64 -> bits 0..5 zero -> never disturbs the bit-4 XOR swizzle).
// NOTE: swizzle XOR must be applied LAST on both sides — granule select is
// byte0 ^ 16 (NOT |16; R5's |16 collided granules when zp&4 set bit 4).
__global__ __launch_bounds__(512, 4) void conv_mfma_lds(
    const float* __restrict__ feat, const int* __restrict__ index,
    const float* __restrict__ bias, const short8* __restrict__ wpack,
    float* __restrict__ out) {
  __shared__ short smem[100 * 18 * 16];   // 57600 B

  const int tid = threadIdx.x;
  const int lane = tid & 63;
  const int wid = tid >> 6;

  // XCD-aware bijective swizzle (3456 % 8 == 0, chunk 432); yt fastest.
  const int d = blockIdx.x;
  int L = (d & 7) * 432 + (d >> 3);
  const int yt = L % NYT;  L /= NYT;
  const int zt = L % NZT;  L /= NZT;
  const int xt = L % NXT;
  const int b  = L / NXT;
  const int x0 = xt * 8, y0 = yt * 8, z0 = zt * 16;

  // B fragments resident in registers (56 VGPRs).
  short8 bw[14];
#pragma unroll
  for (int t = 0; t < 14; ++t) bw[t] = wpack[t * 64 + lane];

  // ---- stage: 100 cols x 18 z-lines, f32 -> bf16 ----
  for (int it = tid; it < 1800; it += 512) {
    const int col = it / 18;
    const int zp  = it - col * 18;
    const int colx = col / 10;
    const int coly = col - colx * 10;
    const int gx = x0 + colx - 1, gy = y0 + coly - 1, gz = z0 + zp - 1;
    const bool ok = ((unsigned)gx < (unsigned)DSZ) &
                    ((unsigned)gy < (unsigned)DSZ) &
                    ((unsigned)gz < (unsigned)DSZ);
    const long off = ok ? ((long)(((b * DSZ + gx) * DSZ + gy) * DSZ + gz) * CIN) : 0;
    const float4* p = reinterpret_cast<const float4*>(feat + off);
    float4 q0 = p[0], q1 = p[1], q2 = p[2], q3 = p[3];
    unsigned m0 = __builtin_amdgcn_perm(__float_as_uint(q0.y), __float_as_uint(q0.x), 0x07060302u);
    unsigned m1 = __builtin_amdgcn_perm(__float_as_uint(q0.w), __float_as_uint(q0.z), 0x07060302u);
    unsigned m2 = __builtin_amdgcn_perm(__float_as_uint(q1.y), __float_as_uint(q1.x), 0x07060302u);
    unsigned m3 = __builtin_amdgcn_perm(__float_as_uint(q1.w), __float_as_uint(q1.z), 0x07060302u);
    unsigned m4 = __builtin_amdgcn_perm(__float_as_uint(q2.y), __float_as_uint(q2.x), 0x07060302u);
    unsigned m5 = __builtin_amdgcn_perm(__float_as_uint(q2.w), __float_as_uint(q2.z), 0x07060302u);
    unsigned m6 = __builtin_amdgcn_perm(__float_as_uint(q3.y), __float_as_uint(q3.x), 0x07060302u);
    unsigned m7 = __builtin_amdgcn_perm(__float_as_uint(q3.w), __float_as_uint(q3.z), 0x07060302u);
    if (!ok) { m0 = m1 = m2 = m3 = m4 = m5 = m6 = m7 = 0u; }
    const int byte0 = (col * 576 + zp * 32) ^ ((zp & 4) << 2);
    *reinterpret_cast<int4*>((char*)smem + byte0)        = make_int4(m0, m1, m2, m3);
    *reinterpret_cast<int4*>((char*)smem + (byte0 ^ 16)) = make_int4(m4, m5, m6, m7);
  }

  // ---- per-lane fragment addresses (computed while stage loads fly) ----
  const int cx = wid;
  const int tp = lane >> 5;
  int pre[3];
#pragma unroll
  for (int dz = 0; dz < 3; ++dz) {
    const int zp = (lane & 15) + dz;
    pre[dz] = (zp * 32 + (lane & 16)) ^ ((zp & 4) << 2);
  }
  int laddr[14];
#pragma unroll
  for (int t = 0; t < 14; ++t) {
    const int tapA = 2 * t;
    const int tapB = (2 * t + 1 <= 26) ? (2 * t + 1) : 26;  // t13: B-weights 0
    const int aA = ((cx + tapA / 9) * 10 + (tapA / 3) % 3) * 576 + pre[tapA % 3];
    const int aB = ((cx + tapB / 9) * 10 + (tapB / 3) % 3) * 576 + pre[tapB % 3];
    laddr[t] = tp ? aB : aA;
  }

  const int fq = lane & 15, hq = lane >> 4;
  const float bf = bias[fq];
  const char* smb = (const char*)smem;

  const int vbase0 = ((b * DSZ + (x0 + cx)) * DSZ + y0) * DSZ + z0;
  const int* ip = index + vbase0 + hq * 4;
  float* op = out + (long)(vbase0 + hq * 4) * NF + fq;

  __syncthreads();

  // ---- compute: 8 cy tiles, addresses = laddr[t] + cy*576 (immediate) ----
#pragma unroll 2
  for (int cy = 0; cy < 8; ++cy) {
    f32x4 acc0 = {0.f, 0.f, 0.f, 0.f};
    f32x4 acc1 = {0.f, 0.f, 0.f, 0.f};
#pragma unroll
    for (int t = 0; t < 14; ++t) {
      I4S8 u;
      u.i = *reinterpret_cast<const int4*>(smb + laddr[t] + cy * 576);
      if (t & 1)
        acc1 = __builtin_amdgcn_mfma_f32_16x16x32_bf16(u.s, bw[t], acc1, 0, 0, 0);
      else
        acc0 = __builtin_amdgcn_mfma_f32_16x16x32_bf16(u.s, bw[t], acc0, 0, 0, 0);
    }
    const int4 iv = *reinterpret_cast<const int4*>(ip);
    op[0 * NF] = iv.x ? (acc0[0] + acc1[0] + bf) : 0.0f;
    op[1 * NF] = iv.y ? (acc0[1] + acc1[1] + bf) : 0.0f;
    op[2 * NF] = iv.z ? (acc0[2] + acc1[2] + bf) : 0.0f;
    op[3 * NF] = iv.w ? (acc0[3] + acc1[3] + bf) : 0.0f;
    ip += DSZ;
    op += (long)DSZ * NF;
  }
}

// ---------------- fallback (tiny ws): round-1 f32 kernel ----------------
__global__ __launch_bounds__(256) void sparse_conv_f32(
    const float* __restrict__ feat, const int* __restrict__ index,
    const float* __restrict__ w, const float* __restrict__ bias,
    float* __restrict__ out) {
  const int v = blockIdx.x * 256 + threadIdx.x;
  const int z = v % DSZ;
  int t = v / DSZ;
  const int y = t % DSZ; t /= DSZ;
  const int x = t % DSZ;
  const int bb = t / DSZ;
  float acc[NF];
#pragma unroll
  for (int f = 0; f < NF; ++f) acc[f] = bias[f];
  const bool active = (index[v] != 0);
#pragma unroll 1
  for (int kx = -1; kx <= 1; ++kx) {
    const int xx = x + kx;
    const bool okx = ((unsigned)xx < (unsigned)DSZ);
#pragma unroll 1
    for (int ky = -1; ky <= 1; ++ky) {
      const int yy = y + ky;
      const bool oky = okx && ((unsigned)yy < (unsigned)DSZ);
#pragma unroll 1
      for (int kz = -1; kz <= 1; ++kz) {
        const int zz = z + kz;
        const bool ok = oky && ((unsigned)zz < (unsigned)DSZ);
        const long long off = ((((long long)bb * DSZ + xx) * DSZ + yy) * DSZ + zz) * CIN;
        float4 q0, q1, q2, q3;
        if (ok) {
          const float4* fp = reinterpret_cast<const float4*>(feat + off);
          q0 = fp[0]; q1 = fp[1]; q2 = fp[2]; q3 = fp[3];
        } else {
          q0 = q1 = q2 = q3 = make_float4(0.f, 0.f, 0.f, 0.f);
        }
        const float fv[CIN] = {q0.x, q0.y, q0.z, q0.w, q1.x, q1.y, q1.z, q1.w,
                               q2.x, q2.y, q2.z, q2.w, q3.x, q3.y, q3.z, q3.w};
        const float* wr = w + ((((kx + 1) * 3 + (ky + 1)) * 3 + (kz + 1)) * CIN) * NF;
#pragma unroll
        for (int ci = 0; ci < CIN; ++ci) {
          const float fvv = fv[ci];
#pragma unroll
          for (int f = 0; f < NF; ++f) acc[f] = fmaf(fvv, wr[ci * NF + f], acc[f]);
        }
      }
    }
  }
  float4* op = reinterpret_cast<float4*>(out + (long long)v * NF);
  if (active) {
    op[0] = make_float4(acc[0], acc[1], acc[2], acc[3]);
    op[1] = make_float4(acc[4], acc[5], acc[6], acc[7]);
    op[2] = make_float4(acc[8], acc[9], acc[10], acc[11]);
    op[3] = make_float4(acc[12], acc[13], acc[14], acc[15]);
  } else {
    const float4 z4 = make_float4(0.f, 0.f, 0.f, 0.f);
    op[0] = z4; op[1] = z4; op[2] = z4; op[3] = z4;
  }
}

extern "C" void kernel_launch(void* const* d_in, const int* in_sizes, int n_in,
                              void* d_out, int out_size, void* d_ws, size_t ws_size,
                              hipStream_t stream) {
  const float* feat  = (const float*)d_in[0];
  const int*   index = (const int*)d_in[1];
  const float* w     = (const float*)d_in[2];
  const float* bias  = (const float*)d_in[3];
  float*       out   = (float*)d_out;

  const int nvox = in_sizes[1];  // 4*96*96*96

  if (ws_size < 14 * 64 * 8 * sizeof(short)) {
    sparse_conv_f32<<<nvox / 256, 256, 0, stream>>>(feat, index, w, bias, out);
    return;
  }

  short* wpack = (short*)d_ws;
  pack_w<<<1, 14 * 64, 0, stream>>>(w, wpack);

  const int blocks = 4 * NXT * NYT * NZT;  // 3456
  conv_mfma_lds<<<blocks, 512, 0, stream>>>(feat, index, bias,
                                            (const short8*)wpack, out);
}